// Round 15
// baseline (127.391 us; speedup 1.0000x reference)
//
#include <hip/hip_runtime.h>
#include <math.h>

#define N_EXP 64
#define TOPK 8
#define TOPK_G 4
#define D_DIM 2048
#define S_TOT 16384
#define RPB 16            // rows per block

typedef _Float16 half8 __attribute__((ext_vector_type(8)));
typedef float f32x4 __attribute__((ext_vector_type(4)));

// kernel 0: split W fp32 -> (Wh, Wl*2^11) fp16. 131072 elems. (R13-proven)
__global__ void split_w_kernel(const float* __restrict__ W,
                               _Float16* __restrict__ Wh,
                               _Float16* __restrict__ Wl) {
    int t = blockIdx.x * blockDim.x + threadIdx.x;
    if (t < N_EXP * D_DIM) {
        float f = W[t];
        _Float16 h = (_Float16)f;
        Wh[t] = h;
        Wl[t] = (_Float16)((f - (float)h) * 2048.0f);
    }
}

// kernel 1: fused fp16x3 MFMA router, expert-split waves.
// Block = 16 rows x 256 thr; wave w owns expert tile w (16 experts) over the
// FULL K=2048 (64 k-steps of 32). Per k-step only 4 loads (2 x float4 + 2 W
// half8); x lines shared by all 4 waves (L1 reuse); no cross-wave reduction.
// Explicit 4-slot circular register prefetch (compile-time slot indices)
// forces >=3 k-steps of loads in flight — the dataflow, not the scheduler,
// carries the pipeline. Numerics = R13 (absmax 4.9e-4).
__launch_bounds__(256)
__global__ void router_kernel(const float* __restrict__ x,
                              const _Float16* __restrict__ Wh,
                              const _Float16* __restrict__ Wl,
                              const float* __restrict__ bias,
                              float* __restrict__ out_idx,
                              float* __restrict__ out_w)
{
    __shared__ float lg[RPB * 68];
    __shared__ float bs[N_EXP];

    const int tid  = threadIdx.x;
    const int wave = tid >> 6;        // expert tile 0..3
    const int lane = tid & 63;
    const int m16  = lane & 15;       // x row within tile / expert within tile
    const int kb   = lane >> 4;       // k sub-block 0..3
    const int row0 = blockIdx.x * RPB;

    if (tid < N_EXP) bs[tid] = bias[tid];

    f32x4 accHH = (f32x4)0.0f, accHL = (f32x4)0.0f, accLH = (f32x4)0.0f;

    const float*    xc  = x  + (size_t)(row0 + m16) * D_DIM + kb * 8;
    const _Float16* bhc = Wh + (size_t)(wave * 16 + m16) * D_DIM + kb * 8;
    const _Float16* blc = Wl + (size_t)(wave * 16 + m16) * D_DIM + kb * 8;

    // 4-slot circular stage (all slot indices compile-time after unroll)
    float4 sa0[4], sa1[4];
    half8  sbh[4], sbl[4];

#define PF(ks, s) do { \
        sa0[s] = *(const float4*)(xc + (ks) * 32); \
        sa1[s] = *(const float4*)(xc + (ks) * 32 + 4); \
        sbh[s] = *(const half8*)(bhc + (ks) * 32); \
        sbl[s] = *(const half8*)(blc + (ks) * 32); \
    } while (0)

    PF(0, 0); PF(1, 1); PF(2, 2);

    for (int ks = 0; ks < 64; ks += 4) {
#pragma unroll
        for (int j = 0; j < 4; ++j) {
            // prefetch ks+j+3 into the slot freed 1 sub-step ago
            if (ks + j + 3 < 64) PF(ks + j + 3, (j + 3) & 3);
            // split x into hi + scaled-lo fp16 (exact residual)
            half8 xh, xl;
            {
                const float v[8] = {sa0[j].x, sa0[j].y, sa0[j].z, sa0[j].w,
                                    sa1[j].x, sa1[j].y, sa1[j].z, sa1[j].w};
#pragma unroll
                for (int i = 0; i < 8; ++i) {
                    _Float16 h = (_Float16)v[i];
                    xh[i] = h;
                    xl[i] = (_Float16)((v[i] - (float)h) * 2048.0f);
                }
            }
            accHH = __builtin_amdgcn_mfma_f32_16x16x32_f16(xh, sbh[j], accHH, 0, 0, 0);
            accHL = __builtin_amdgcn_mfma_f32_16x16x32_f16(xh, sbl[j], accHL, 0, 0, 0);
            accLH = __builtin_amdgcn_mfma_f32_16x16x32_f16(xl, sbh[j], accLH, 0, 0, 0);
        }
    }
#undef PF

    // combine terms, write logits (wave w -> expert cols w*16..w*16+15)
    {
        const float inv2048 = 1.0f / 2048.0f;
#pragma unroll
        for (int r = 0; r < 4; ++r) {
            const float val = accHH[r] + (accHL[r] + accLH[r]) * inv2048;
            lg[(kb * 4 + r) * 68 + wave * 16 + m16] = val;  // D: row=(lane>>4)*4+r, col=lane&15
        }
    }
    __syncthreads();

    // sigmoid in place (R13-proven)
    if (tid < RPB * 8) {
        const int rg = tid >> 3, sl = tid & 7;
#pragma unroll
        for (int j = 0; j < 8; ++j) {
            const int idx = rg * 68 + sl * 8 + j;
            lg[idx] = 1.0f / (1.0f + expf(-lg[idx]));
        }
    }
    __syncthreads();

    // grouped top-k: R7-proven parallel selection (8 sublanes per row)
    if (tid < RPB * 8) {
        const int rg = tid >> 3;
        const int sl = tid & 7;
        const int row = row0 + rg;

        float bsc[8];
        float gm = -INFINITY;
#pragma unroll
        for (int j = 0; j < 8; ++j) {
            bsc[j] = lg[rg * 68 + sl * 8 + j] + bs[sl * 8 + j];
            gm = fmaxf(gm, bsc[j]);
        }

        int grank = 0;
#pragma unroll
        for (int s = 1; s < 8; ++s) {
            float og = __shfl_xor(gm, s, 8);
            int   osl = sl ^ s;
            if (og > gm || (og == gm && osl < sl)) ++grank;
        }
        unsigned alive = (grank < TOPK_G) ? 0xFFu : 0u;

        float wsum = 0.f;
        float myw = 0.f;
        const int orow = row * TOPK;
        for (int k = 0; k < TOPK; ++k) {
            float bv = -INFINITY; int be = 9999;
#pragma unroll
            for (int j = 0; j < 8; ++j) {
                if (alive & (1u << j)) {
                    if (bsc[j] > bv) { bv = bsc[j]; be = sl * 8 + j; }
                }
            }
#pragma unroll
            for (int s = 1; s < 8; s <<= 1) {
                float ov = __shfl_xor(bv, s, 8);
                int   oe = __shfl_xor(be, s, 8);
                if (ov > bv || (ov == bv && oe < be)) { bv = ov; be = oe; }
            }
            const float wr = lg[rg * 68 + be];   // broadcast read of sigmoid score
            wsum += wr;
            if ((be >> 3) == sl) alive &= ~(1u << (be & 7));
            if (sl == k) { out_idx[orow + k] = (float)be; myw = wr; }
        }
        const float inv = 1.0f / (wsum + 1e-20f);
        out_w[orow + sl] = myw * inv;
    }
}

extern "C" void kernel_launch(void* const* d_in, const int* in_sizes, int n_in,
                              void* d_out, int out_size, void* d_ws, size_t ws_size,
                              hipStream_t stream) {
    const float* x    = (const float*)d_in[0];
    const float* W    = (const float*)d_in[1];
    const float* bias = (const float*)d_in[2];
    float* out = (float*)d_out;

    _Float16* Wh = (_Float16*)d_ws;                      // 256 KB
    _Float16* Wl = (_Float16*)((char*)d_ws + 262144);    // 256 KB

    hipLaunchKernelGGL(split_w_kernel, dim3((N_EXP * D_DIM + 255) / 256), dim3(256),
                       0, stream, W, Wh, Wl);
    hipLaunchKernelGGL(router_kernel, dim3(S_TOT / RPB), dim3(256),
                       0, stream, x, Wh, Wl, bias, out, out + S_TOT * TOPK);
}

// Round 16
// 62.913 us; speedup vs baseline: 2.0249x; 2.0249x over previous
//
#include <hip/hip_runtime.h>
#include <math.h>

#define N_EXP 64
#define TOPK 8
#define TOPK_G 4
#define D_DIM 2048
#define S_TOT 16384
#define RPB 32            // rows per block
#define NBUF 5            // LDS pipeline depth (stage 4 ahead)
#define NCH 64            // K chunks of 32

typedef _Float16 half8 __attribute__((ext_vector_type(8)));
typedef float f32x4 __attribute__((ext_vector_type(4)));

typedef __attribute__((address_space(1))) const unsigned int ga_u32;
typedef __attribute__((address_space(3))) unsigned int ls_u32;
#define GLL(src, dst) \
    __builtin_amdgcn_global_load_lds((ga_u32*)(src), (ls_u32*)(dst), 16, 0, 0)
#define VM(n) asm volatile("s_waitcnt vmcnt(" #n ")" ::: "memory")
#define BAR() do { asm volatile("" ::: "memory"); \
                   __builtin_amdgcn_s_barrier(); \
                   asm volatile("" ::: "memory"); } while (0)

// kernel 0: split W fp32 -> fp16 (h, l*2^11) packed in the LDS-image fragment
// layout: per chunk c (4096 halfs): Wh[tile t4][e4*32 + slot*8], Wl at +2048,
// slot = (kb + (e4>>1)) & 3  (bank-spread so B-frag b128 reads are 2-way max).
__global__ void split_w_kernel(const float* __restrict__ W,
                               _Float16* __restrict__ wsg) {
    int t = blockIdx.x * blockDim.x + threadIdx.x;   // 64c * 64e * 4kb = 16384
    if (t >= NCH * N_EXP * 4) return;
    const int c  = t >> 8;
    const int e  = (t >> 2) & 63;
    const int kb = t & 3;
    const int e4 = e & 15, t4 = e >> 4;
    const int slot = (kb + (e4 >> 1)) & 3;
    _Float16* dh = wsg + (size_t)c * 4096 + t4 * 512 + e4 * 32 + slot * 8;
    _Float16* dl = dh + 2048;
    const float* s = W + (size_t)e * D_DIM + c * 32 + kb * 8;
#pragma unroll
    for (int i = 0; i < 8; ++i) {
        float f = s[i];
        _Float16 h = (_Float16)f;
        dh[i] = h;
        dl[i] = (_Float16)((f - (float)h) * 2048.0f);
    }
}

// kernel 1: fused fp16x3 MFMA router, async-DMA pipelined.
// 256 thr = 4 waves; wave w owns expert tile w (16 experts) over full K.
// 64 chunks of K=32; 5-buffer LDS; global_load_lds (no VGPR staging — the
// compiler cannot re-serialize it); vmcnt(12) = 4 chunks in flight.
// x staged via pre-swizzled per-lane global source: granule (r,kq) at LDS pos
// r*8 + ((kq+r)&7)  -> A-frag b128 reads 2-way conflict max.
__launch_bounds__(256)
__global__ void router_kernel(const float* __restrict__ x,
                              const _Float16* __restrict__ wsg,
                              const float* __restrict__ bias,
                              float* __restrict__ out_idx,
                              float* __restrict__ out_w)
{
    __shared__ __align__(16) float    xs[NBUF][1024];   // 20 KB: x chunks [32r][32k] swizzled
    __shared__ __align__(16) _Float16 wh[NBUF][4096];   // 40 KB: Wh||Wl chunks
    __shared__ float lg[RPB * 68];
    __shared__ float bs[N_EXP];

    const int tid  = threadIdx.x;
    const int wave = tid >> 6;
    const int lane = tid & 63;
    const int m16  = lane & 15;
    const int kb   = lane >> 4;
    const int row0 = blockIdx.x * RPB;

    // staging sources
    const int g   = wave * 64 + lane;        // x granule this lane stages
    const int gr  = g >> 3, gc = g & 7;
    const int kqs = (gc - gr) & 7;           // inverse swizzle on global src
    const float*    xsrc = x + (size_t)(row0 + gr) * D_DIM + kqs * 4;
    const _Float16* wsrc = wsg + wave * 512 + lane * 8;

#define STAGE(c, b) do { \
        GLL(xsrc + (size_t)(c) * 32,          &xs[b][wave * 256]); \
        GLL(wsrc + (size_t)(c) * 4096,        &wh[b][wave * 512]); \
        GLL(wsrc + (size_t)(c) * 4096 + 2048, &wh[b][2048 + wave * 512]); \
    } while (0)

    f32x4 accHH[2], accHL[2], accLH[2];
#pragma unroll
    for (int mt = 0; mt < 2; ++mt) {
        accHH[mt] = (f32x4)0.0f; accHL[mt] = (f32x4)0.0f; accLH[mt] = (f32x4)0.0f;
    }

#define COMPUTE(b) do { \
        const int boff = m16 * 32 + ((kb + (m16 >> 1)) & 3) * 8; \
        const half8 bh = *(const half8*)&wh[b][wave * 512 + boff]; \
        const half8 bl = *(const half8*)&wh[b][2048 + wave * 512 + boff]; \
        _Pragma("unroll") \
        for (int mt = 0; mt < 2; ++mt) { \
            const int r  = mt * 16 + m16; \
            const int p0 = r * 8 + ((kb * 2 + r) & 7); \
            const int p1 = r * 8 + ((kb * 2 + 1 + r) & 7); \
            const float4 f0 = *(const float4*)&xs[b][p0 * 4]; \
            const float4 f1 = *(const float4*)&xs[b][p1 * 4]; \
            const float v[8] = {f0.x, f0.y, f0.z, f0.w, f1.x, f1.y, f1.z, f1.w}; \
            half8 xh, xl; \
            _Pragma("unroll") \
            for (int i = 0; i < 8; ++i) { \
                _Float16 h = (_Float16)v[i]; \
                xh[i] = h; \
                xl[i] = (_Float16)((v[i] - (float)h) * 2048.0f); \
            } \
            accHH[mt] = __builtin_amdgcn_mfma_f32_16x16x32_f16(xh, bh, accHH[mt], 0, 0, 0); \
            accHL[mt] = __builtin_amdgcn_mfma_f32_16x16x32_f16(xh, bl, accHL[mt], 0, 0, 0); \
            accLH[mt] = __builtin_amdgcn_mfma_f32_16x16x32_f16(xl, bh, accLH[mt], 0, 0, 0); \
        } \
    } while (0)

    // prologue: stage chunks 0..3
    STAGE(0, 0); STAGE(1, 1); STAGE(2, 2); STAGE(3, 3);

    int buf = 0;
    for (int c = 0; c < NCH; ++c) {
        int nb = buf + 4; if (nb >= NBUF) nb -= NBUF;
        if (c + 4 < NCH) { STAGE(c + 4, nb); VM(12); }
        else if (c == NCH - 4) VM(9);
        else if (c == NCH - 3) VM(6);
        else if (c == NCH - 2) VM(3);
        else                   VM(0);
        BAR();               // chunk c fully landed (all waves past their vmcnt)
        COMPUTE(buf);
        BAR();               // chunk-c reads done before buf is re-staged
        if (++buf == NBUF) buf = 0;
    }
#undef STAGE
#undef COMPUTE

    // epilogue: combine terms -> logits (D: row=(lane>>4)*4+r, col=lane&15)
    {
        const float inv2048 = 1.0f / 2048.0f;
#pragma unroll
        for (int mt = 0; mt < 2; ++mt)
#pragma unroll
            for (int r = 0; r < 4; ++r) {
                const float val = accHH[mt][r] + (accHL[mt][r] + accLH[mt][r]) * inv2048;
                lg[(mt * 16 + kb * 4 + r) * 68 + wave * 16 + m16] = val;
            }
    }
    if (tid < N_EXP) bs[tid] = bias[tid];
    __syncthreads();

    // sigmoid in place (32 rows x 64 experts, 8 per thread)
    {
        const int rg = tid >> 3, sl = tid & 7;
#pragma unroll
        for (int j = 0; j < 8; ++j) {
            const int idx = rg * 68 + sl * 8 + j;
            lg[idx] = 1.0f / (1.0f + expf(-lg[idx]));
        }
    }
    __syncthreads();

    // grouped top-k: R7-proven parallel selection (ties -> lower index)
    {
        const int rg = tid >> 3;
        const int sl = tid & 7;
        const int row = row0 + rg;

        float bsc[8];
        float gm = -INFINITY;
#pragma unroll
        for (int j = 0; j < 8; ++j) {
            bsc[j] = lg[rg * 68 + sl * 8 + j] + bs[sl * 8 + j];
            gm = fmaxf(gm, bsc[j]);
        }

        int grank = 0;
#pragma unroll
        for (int s = 1; s < 8; ++s) {
            float og = __shfl_xor(gm, s, 8);
            int   osl = sl ^ s;
            if (og > gm || (og == gm && osl < sl)) ++grank;
        }
        unsigned alive = (grank < TOPK_G) ? 0xFFu : 0u;

        float wsum = 0.f;
        float myw = 0.f;
        const int orow = row * TOPK;
        for (int k = 0; k < TOPK; ++k) {
            float bv = -INFINITY; int be = 9999;
#pragma unroll
            for (int j = 0; j < 8; ++j) {
                if (alive & (1u << j)) {
                    if (bsc[j] > bv) { bv = bsc[j]; be = sl * 8 + j; }
                }
            }
#pragma unroll
            for (int s = 1; s < 8; s <<= 1) {
                float ov = __shfl_xor(bv, s, 8);
                int   oe = __shfl_xor(be, s, 8);
                if (ov > bv || (ov == bv && oe < be)) { bv = ov; be = oe; }
            }
            const float wr = lg[rg * 68 + be];
            wsum += wr;
            if ((be >> 3) == sl) alive &= ~(1u << (be & 7));
            if (sl == k) { out_idx[orow + k] = (float)be; myw = wr; }
        }
        const float inv = 1.0f / (wsum + 1e-20f);
        out_w[orow + sl] = myw * inv;
    }
}

extern "C" void kernel_launch(void* const* d_in, const int* in_sizes, int n_in,
                              void* d_out, int out_size, void* d_ws, size_t ws_size,
                              hipStream_t stream) {
    const float* x    = (const float*)d_in[0];
    const float* W    = (const float*)d_in[1];
    const float* bias = (const float*)d_in[2];
    float* out = (float*)d_out;
    _Float16* wsg = (_Float16*)d_ws;   // 512 KB fragment-packed W halves

    hipLaunchKernelGGL(split_w_kernel, dim3(NCH * N_EXP * 4 / 256), dim3(256),
                       0, stream, W, wsg);
    hipLaunchKernelGGL(router_kernel, dim3(S_TOT / RPB), dim3(256),
                       0, stream, x, wsg, bias, out, out + S_TOT * TOPK);
}

// Round 17
// 55.448 us; speedup vs baseline: 2.2975x; 1.1346x over previous
//
#include <hip/hip_runtime.h>
#include <math.h>

#define N_EXP 64
#define TOPK 8
#define TOPK_G 4
#define D_DIM 2048
#define S_TOT 16384
#define RPB 32            // rows per block
#define NBUF 3            // LDS pipeline depth (stage 2 ahead)
#define NCH 32            // K chunks of 64

typedef _Float16 half8 __attribute__((ext_vector_type(8)));
typedef float f32x4 __attribute__((ext_vector_type(4)));

typedef __attribute__((address_space(1))) const unsigned int ga_u32;
typedef __attribute__((address_space(3))) unsigned int ls_u32;
#define GLL(src, dst) \
    __builtin_amdgcn_global_load_lds((ga_u32*)(src), (ls_u32*)(dst), 16, 0, 0)
#define VM(n) asm volatile("s_waitcnt vmcnt(" #n ")" ::: "memory")
#define BAR() do { asm volatile("" ::: "memory"); \
                   __builtin_amdgcn_s_barrier(); \
                   asm volatile("" ::: "memory"); } while (0)

// kernel 0: split W fp32 -> fp16 (h, l*2^11), packed per K=64 chunk in the
// LDS-image layout: chunk c (8192 halfs) = Wh[(kh*4+t4)*512 + m16*32 + slot*8]
// (4096) || Wl (4096), slot = (kb + (m16>>1)) & 3 (R16-proven bank spread).
__global__ void split_w_kernel(const float* __restrict__ W,
                               _Float16* __restrict__ wsg) {
    int t = blockIdx.x * blockDim.x + threadIdx.x;   // 32c*2kh*4t4*16m*4kb = 16384
    if (t >= 16384) return;
    const int c   = t >> 9;
    const int kh  = (t >> 8) & 1;
    const int t4  = (t >> 6) & 3;
    const int m16 = (t >> 2) & 15;
    const int kb  = t & 3;
    const int slot = (kb + (m16 >> 1)) & 3;
    _Float16* dh = wsg + (size_t)c * 8192 + (kh * 4 + t4) * 512 + m16 * 32 + slot * 8;
    _Float16* dl = dh + 4096;
    const float* s = W + (size_t)(t4 * 16 + m16) * D_DIM + c * 64 + kh * 32 + kb * 8;
#pragma unroll
    for (int i = 0; i < 8; ++i) {
        float f = s[i];
        _Float16 h = (_Float16)f;
        dh[i] = h;
        dl[i] = (_Float16)((f - (float)h) * 2048.0f);
    }
}

// kernel 1: fused fp16x3 MFMA router, async-DMA pipelined (R16 skeleton).
// 512 thr = 8 waves: wave w = (kh=w>>2, et=w&3) — expert tile et over K-half
// kh. 32 chunks of K=64; NBUF=3; 3 GLL/wave/chunk; vmcnt(6) = 2 chunks ahead.
// lg/bias OVERLAY the xs staging buffers after the K-loop. 2-phase kh-reduce.
__launch_bounds__(512)
__global__ void router_kernel(const float* __restrict__ x,
                              const _Float16* __restrict__ wsg,
                              const float* __restrict__ bias,
                              float* __restrict__ out_idx,
                              float* __restrict__ out_w)
{
    __shared__ __align__(16) float    xs[NBUF][2048];   // 24 KB x chunks [32r][64k] swz
    __shared__ __align__(16) _Float16 wh[NBUF][8192];   // 48 KB Wh||Wl chunks

    const int tid  = threadIdx.x;
    const int w    = tid >> 6;        // wave 0..7
    const int et   = w & 3;           // expert tile
    const int kh   = w >> 2;          // K half within chunk
    const int lane = tid & 63;
    const int m16  = lane & 15;
    const int kb   = lane >> 4;
    const int row0 = blockIdx.x * RPB;

    // x staging: lane stages granule gidx (16B) at LDS pos = gidx, from the
    // inverse-swizzled global position (swizzle spreads by row within 32k half)
    const int gidx = w * 64 + lane;         // 0..511
    const int gr = gidx >> 4;               // row 0..31
    const int gs = gidx & 15;
    const int gh = gs >> 3;                 // k-half of granule
    const int gq = ((gs & 7) - gr) & 7;
    const float*    xsrc = x + (size_t)(row0 + gr) * D_DIM + gh * 32 + gq * 4;
    const _Float16* wsrc = wsg + w * 512 + lane * 8;

#define STAGE(c, b) do { \
        GLL(xsrc + (size_t)(c) * 64,           &xs[b][w * 256]); \
        GLL(wsrc + (size_t)(c) * 8192,         &wh[b][w * 512]); \
        GLL(wsrc + (size_t)(c) * 8192 + 4096,  &wh[b][4096 + w * 512]); \
    } while (0)

    f32x4 accHH[2], accHL[2], accLH[2];
#pragma unroll
    for (int mt = 0; mt < 2; ++mt) {
        accHH[mt] = (f32x4)0.0f; accHL[mt] = (f32x4)0.0f; accLH[mt] = (f32x4)0.0f;
    }

#define COMPUTE(b) do { \
        const int boff = m16 * 32 + ((kb + (m16 >> 1)) & 3) * 8; \
        const half8 bh = *(const half8*)&wh[b][w * 512 + boff]; \
        const half8 bl = *(const half8*)&wh[b][4096 + w * 512 + boff]; \
        _Pragma("unroll") \
        for (int mt = 0; mt < 2; ++mt) { \
            const int rr = mt * 16 + m16; \
            const int p0 = rr * 16 + kh * 8 + ((kb * 2 + rr) & 7); \
            const int p1 = rr * 16 + kh * 8 + ((kb * 2 + 1 + rr) & 7); \
            const float4 f0 = *(const float4*)&xs[b][p0 * 4]; \
            const float4 f1 = *(const float4*)&xs[b][p1 * 4]; \
            const float v[8] = {f0.x, f0.y, f0.z, f0.w, f1.x, f1.y, f1.z, f1.w}; \
            half8 xh, xl; \
            _Pragma("unroll") \
            for (int i = 0; i < 8; ++i) { \
                _Float16 h = (_Float16)v[i]; \
                xh[i] = h; \
                xl[i] = (_Float16)((v[i] - (float)h) * 2048.0f); \
            } \
            accHH[mt] = __builtin_amdgcn_mfma_f32_16x16x32_f16(xh, bh, accHH[mt], 0, 0, 0); \
            accHL[mt] = __builtin_amdgcn_mfma_f32_16x16x32_f16(xh, bl, accHL[mt], 0, 0, 0); \
            accLH[mt] = __builtin_amdgcn_mfma_f32_16x16x32_f16(xl, bh, accLH[mt], 0, 0, 0); \
        } \
    } while (0)

    // prologue: stage chunks 0,1
    STAGE(0, 0); STAGE(1, 1);

    int buf = 0;
    for (int c = 0; c < NCH; ++c) {
        int nb = buf + 2; if (nb >= NBUF) nb -= NBUF;
        if (c + 2 < NCH)      { STAGE(c + 2, nb); VM(6); }
        else if (c == NCH - 2) VM(3);
        else                   VM(0);
        BAR();               // chunk c fully landed for all waves
        COMPUTE(buf);
        BAR();               // chunk-c reads done before this buffer re-staged
        if (++buf == NBUF) buf = 0;
    }
#undef STAGE
#undef COMPUTE

    // ---- epilogue: lg/bias overlay the xs buffers (safe after final BAR) ----
    float* lgp = (float*)&xs[0][0];        // RPB*68 = 2176 floats
    float* bsp = lgp + RPB * 68;           // 64 floats

    if (tid < N_EXP) bsp[tid] = bias[tid];

    const float inv2048 = 1.0f / 2048.0f;
    // 2-phase kh reduction into lg (D frag: row = mt*16 + kb*4 + r, col = et*16+m16)
    if (kh == 0) {
#pragma unroll
        for (int mt = 0; mt < 2; ++mt)
#pragma unroll
            for (int r = 0; r < 4; ++r)
                lgp[(mt * 16 + kb * 4 + r) * 68 + et * 16 + m16] =
                    accHH[mt][r] + (accHL[mt][r] + accLH[mt][r]) * inv2048;
    }
    __syncthreads();
    if (kh == 1) {
#pragma unroll
        for (int mt = 0; mt < 2; ++mt)
#pragma unroll
            for (int r = 0; r < 4; ++r)
                lgp[(mt * 16 + kb * 4 + r) * 68 + et * 16 + m16] +=
                    accHH[mt][r] + (accHL[mt][r] + accLH[mt][r]) * inv2048;
    }
    __syncthreads();

    // sigmoid in place (32 rows x 64 experts; threads 0..255)
    if (tid < RPB * 8) {
        const int rg = tid >> 3, sl = tid & 7;
#pragma unroll
        for (int j = 0; j < 8; ++j) {
            const int idx = rg * 68 + sl * 8 + j;
            lgp[idx] = 1.0f / (1.0f + expf(-lgp[idx]));
        }
    }
    __syncthreads();

    // grouped top-k: R7-proven parallel selection (ties -> lower index)
    if (tid < RPB * 8) {
        const int rg = tid >> 3;
        const int sl = tid & 7;
        const int row = row0 + rg;

        float bsc[8];
        float gm = -INFINITY;
#pragma unroll
        for (int j = 0; j < 8; ++j) {
            bsc[j] = lgp[rg * 68 + sl * 8 + j] + bsp[sl * 8 + j];
            gm = fmaxf(gm, bsc[j]);
        }

        int grank = 0;
#pragma unroll
        for (int s = 1; s < 8; ++s) {
            float og = __shfl_xor(gm, s, 8);
            int   osl = sl ^ s;
            if (og > gm || (og == gm && osl < sl)) ++grank;
        }
        unsigned alive = (grank < TOPK_G) ? 0xFFu : 0u;

        float wsum = 0.f;
        float myw = 0.f;
        const int orow = row * TOPK;
        for (int k = 0; k < TOPK; ++k) {
            float bv = -INFINITY; int be = 9999;
#pragma unroll
            for (int j = 0; j < 8; ++j) {
                if (alive & (1u << j)) {
                    if (bsc[j] > bv) { bv = bsc[j]; be = sl * 8 + j; }
                }
            }
#pragma unroll
            for (int s = 1; s < 8; s <<= 1) {
                float ov = __shfl_xor(bv, s, 8);
                int   oe = __shfl_xor(be, s, 8);
                if (ov > bv || (ov == bv && oe < be)) { bv = ov; be = oe; }
            }
            const float wr = lgp[rg * 68 + be];
            wsum += wr;
            if ((be >> 3) == sl) alive &= ~(1u << (be & 7));
            if (sl == k) { out_idx[orow + k] = (float)be; myw = wr; }
        }
        const float inv = 1.0f / (wsum + 1e-20f);
        out_w[orow + sl] = myw * inv;
    }
}

extern "C" void kernel_launch(void* const* d_in, const int* in_sizes, int n_in,
                              void* d_out, int out_size, void* d_ws, size_t ws_size,
                              hipStream_t stream) {
    const float* x    = (const float*)d_in[0];
    const float* W    = (const float*)d_in[1];
    const float* bias = (const float*)d_in[2];
    float* out = (float*)d_out;
    _Float16* wsg = (_Float16*)d_ws;   // 512 KB fragment-packed W halves

    hipLaunchKernelGGL(split_w_kernel, dim3(16384 / 256), dim3(256),
                       0, stream, W, wsg);
    hipLaunchKernelGGL(router_kernel, dim3(S_TOT / RPB), dim3(512),
                       0, stream, x, wsg, bias, out, out + S_TOT * TOPK);
}

// Round 18
// 50.049 us; speedup vs baseline: 2.5453x; 1.1079x over previous
//
#include <hip/hip_runtime.h>
#include <math.h>

#define N_EXP 64
#define TOPK 8
#define TOPK_G 4
#define D_DIM 2048
#define S_TOT 16384
#define RPB 64            // rows per block
#define NBUF 4            // LDS pipeline depth (stage 3 ahead)
#define NCH 32            // K chunks of 64

typedef _Float16 half8 __attribute__((ext_vector_type(8)));
typedef float f32x4 __attribute__((ext_vector_type(4)));

typedef __attribute__((address_space(1))) const unsigned int ga_u32;
typedef __attribute__((address_space(3))) unsigned int ls_u32;
#define GLL(src, dst) \
    __builtin_amdgcn_global_load_lds((ga_u32*)(src), (ls_u32*)(dst), 16, 0, 0)
#define VM(n) asm volatile("s_waitcnt vmcnt(" #n ")" ::: "memory")
#define BAR() do { asm volatile("" ::: "memory"); \
                   __builtin_amdgcn_s_barrier(); \
                   asm volatile("" ::: "memory"); } while (0)

// kernel 0: split W fp32 -> fp16 (h, l*2^11), packed per K=64 chunk
// (R17-proven verbatim): chunk c (8192 halfs) = Wh[(kh*4+t4)*512 + m16*32 +
// slot*8] (4096) || Wl (4096), slot = (kb + (m16>>1)) & 3.
__global__ void split_w_kernel(const float* __restrict__ W,
                               _Float16* __restrict__ wsg) {
    int t = blockIdx.x * blockDim.x + threadIdx.x;   // 32c*2kh*4t4*16m*4kb = 16384
    if (t >= 16384) return;
    const int c   = t >> 9;
    const int kh  = (t >> 8) & 1;
    const int t4  = (t >> 6) & 3;
    const int m16 = (t >> 2) & 15;
    const int kb  = t & 3;
    const int slot = (kb + (m16 >> 1)) & 3;
    _Float16* dh = wsg + (size_t)c * 8192 + (kh * 4 + t4) * 512 + m16 * 32 + slot * 8;
    _Float16* dl = dh + 4096;
    const float* s = W + (size_t)(t4 * 16 + m16) * D_DIM + c * 64 + kh * 32 + kb * 8;
#pragma unroll
    for (int i = 0; i < 8; ++i) {
        float f = s[i];
        _Float16 h = (_Float16)f;
        dh[i] = h;
        dl[i] = (_Float16)((f - (float)h) * 2048.0f);
    }
}

// kernel 1: fused fp16x3 MFMA router, async-DMA pipelined (R16/R17 skeleton).
// 1024 thr = 16 waves: w = (rh=w>>3, kh=(w>>2)&1, et=w&3). Wave computes
// rows rh*32 + mt*16 + m16 (mt 0..1), expert tile et, K-half kh of each
// chunk. 32 chunks of K=64; NBUF=4 lookahead 3; 2 GLL/lane/chunk; vmcnt(6).
// lg/bias overlay xs after the K-loop; 2-phase kh-reduce.
__launch_bounds__(1024)
__global__ void router_kernel(const float* __restrict__ x,
                              const _Float16* __restrict__ wsg,
                              const float* __restrict__ bias,
                              float* __restrict__ out_idx,
                              float* __restrict__ out_w)
{
    __shared__ __align__(16) float    xs[NBUF][4096];   // 64 KB x chunks [64r][64k] swz
    __shared__ __align__(16) _Float16 wh[NBUF][8192];   // 64 KB Wh||Wl chunks

    const int tid  = threadIdx.x;
    const int w    = tid >> 6;        // wave 0..15
    const int et   = w & 3;           // expert tile
    const int kh   = (w >> 2) & 1;    // K half within chunk
    const int rh   = w >> 3;          // row half
    const int lane = tid & 63;
    const int m16  = lane & 15;
    const int kb   = lane >> 4;
    const int row0 = blockIdx.x * RPB;

    // x staging: thread stages granule gidx (16B) at LDS float pos gidx*4,
    // from the inverse-swizzled global position (slot = (quad + row) & 7)
    const int gidx = tid;                   // 0..1023
    const int gr = gidx >> 4;               // row 0..63
    const int gs = gidx & 15;
    const int gh = gs >> 3;                 // k-half of granule
    const int gq = ((gs & 7) - gr) & 7;     // global quad for this slot
    const float*    xsrc = x + (size_t)(row0 + gr) * D_DIM + gh * 32 + gq * 4;
    const _Float16* wsrc = wsg + (size_t)tid * 8;

#define STAGE(c, b) do { \
        GLL(xsrc + (size_t)(c) * 64, &xs[b][w * 256]); \
        GLL(wsrc + (size_t)(c) * 8192, &wh[b][w * 512]); \
    } while (0)

    f32x4 accHH[2], accHL[2], accLH[2];
#pragma unroll
    for (int mt = 0; mt < 2; ++mt) {
        accHH[mt] = (f32x4)0.0f; accHL[mt] = (f32x4)0.0f; accLH[mt] = (f32x4)0.0f;
    }

#define COMPUTE(b) do { \
        const int boff = (kh * 4 + et) * 512 + m16 * 32 + ((kb + (m16 >> 1)) & 3) * 8; \
        const half8 bh = *(const half8*)&wh[b][boff]; \
        const half8 bl = *(const half8*)&wh[b][4096 + boff]; \
        _Pragma("unroll") \
        for (int mt = 0; mt < 2; ++mt) { \
            const int rr = rh * 32 + mt * 16 + m16; \
            const int p0 = rr * 16 + kh * 8 + ((kb * 2 + rr) & 7); \
            const int p1 = rr * 16 + kh * 8 + ((kb * 2 + 1 + rr) & 7); \
            const float4 f0 = *(const float4*)&xs[b][p0 * 4]; \
            const float4 f1 = *(const float4*)&xs[b][p1 * 4]; \
            const float v[8] = {f0.x, f0.y, f0.z, f0.w, f1.x, f1.y, f1.z, f1.w}; \
            half8 xh, xl; \
            _Pragma("unroll") \
            for (int i = 0; i < 8; ++i) { \
                _Float16 h = (_Float16)v[i]; \
                xh[i] = h; \
                xl[i] = (_Float16)((v[i] - (float)h) * 2048.0f); \
            } \
            accHH[mt] = __builtin_amdgcn_mfma_f32_16x16x32_f16(xh, bh, accHH[mt], 0, 0, 0); \
            accHL[mt] = __builtin_amdgcn_mfma_f32_16x16x32_f16(xh, bl, accHL[mt], 0, 0, 0); \
            accLH[mt] = __builtin_amdgcn_mfma_f32_16x16x32_f16(xl, bh, accLH[mt], 0, 0, 0); \
        } \
    } while (0)

    // prologue: stage chunks 0..2
    STAGE(0, 0); STAGE(1, 1); STAGE(2, 2);

    for (int c = 0; c < NCH; ++c) {
        if (c + 3 < NCH)        { STAGE(c + 3, (c + 3) & 3); VM(6); }
        else if (c == NCH - 3)  VM(4);
        else if (c == NCH - 2)  VM(2);
        else                    VM(0);
        BAR();               // chunk c fully landed for all waves
        COMPUTE(c & 3);
        BAR();               // chunk-c reads done before this buffer re-staged
    }
#undef STAGE
#undef COMPUTE

    // ---- epilogue: lg/bias overlay the xs buffers (safe after final BAR) ----
    float* lgp = (float*)&xs[0][0];        // RPB*68 = 4352 floats
    float* bsp = lgp + RPB * 68;           // 64 floats

    if (tid < N_EXP) bsp[tid] = bias[tid];

    const float inv2048 = 1.0f / 2048.0f;
    // 2-phase kh reduction (D frag: row = rh*32 + mt*16 + kb*4 + r, col = et*16+m16)
    if (kh == 0) {
#pragma unroll
        for (int mt = 0; mt < 2; ++mt)
#pragma unroll
            for (int r = 0; r < 4; ++r)
                lgp[(rh * 32 + mt * 16 + kb * 4 + r) * 68 + et * 16 + m16] =
                    accHH[mt][r] + (accHL[mt][r] + accLH[mt][r]) * inv2048;
    }
    __syncthreads();
    if (kh == 1) {
#pragma unroll
        for (int mt = 0; mt < 2; ++mt)
#pragma unroll
            for (int r = 0; r < 4; ++r)
                lgp[(rh * 32 + mt * 16 + kb * 4 + r) * 68 + et * 16 + m16] +=
                    accHH[mt][r] + (accHL[mt][r] + accLH[mt][r]) * inv2048;
    }
    __syncthreads();

    // sigmoid in place (64 rows x 64 experts; threads 0..511)
    if (tid < RPB * 8) {
        const int rg = tid >> 3, sl = tid & 7;
#pragma unroll
        for (int j = 0; j < 8; ++j) {
            const int idx = rg * 68 + sl * 8 + j;
            lgp[idx] = 1.0f / (1.0f + expf(-lgp[idx]));
        }
    }
    __syncthreads();

    // grouped top-k: R7-proven parallel selection (ties -> lower index)
    if (tid < RPB * 8) {
        const int rg = tid >> 3;
        const int sl = tid & 7;
        const int row = row0 + rg;

        float bsc[8];
        float gm = -INFINITY;
#pragma unroll
        for (int j = 0; j < 8; ++j) {
            bsc[j] = lgp[rg * 68 + sl * 8 + j] + bsp[sl * 8 + j];
            gm = fmaxf(gm, bsc[j]);
        }

        int grank = 0;
#pragma unroll
        for (int s = 1; s < 8; ++s) {
            float og = __shfl_xor(gm, s, 8);
            int   osl = sl ^ s;
            if (og > gm || (og == gm && osl < sl)) ++grank;
        }
        unsigned alive = (grank < TOPK_G) ? 0xFFu : 0u;

        float wsum = 0.f;
        float myw = 0.f;
        const int orow = row * TOPK;
        for (int k = 0; k < TOPK; ++k) {
            float bv = -INFINITY; int be = 9999;
#pragma unroll
            for (int j = 0; j < 8; ++j) {
                if (alive & (1u << j)) {
                    if (bsc[j] > bv) { bv = bsc[j]; be = sl * 8 + j; }
                }
            }
#pragma unroll
            for (int s = 1; s < 8; s <<= 1) {
                float ov = __shfl_xor(bv, s, 8);
                int   oe = __shfl_xor(be, s, 8);
                if (ov > bv || (ov == bv && oe < be)) { bv = ov; be = oe; }
            }
            const float wr = lgp[rg * 68 + be];
            wsum += wr;
            if ((be >> 3) == sl) alive &= ~(1u << (be & 7));
            if (sl == k) { out_idx[orow + k] = (float)be; myw = wr; }
        }
        const float inv = 1.0f / (wsum + 1e-20f);
        out_w[orow + sl] = myw * inv;
    }
}

extern "C" void kernel_launch(void* const* d_in, const int* in_sizes, int n_in,
                              void* d_out, int out_size, void* d_ws, size_t ws_size,
                              hipStream_t stream) {
    const float* x    = (const float*)d_in[0];
    const float* W    = (const float*)d_in[1];
    const float* bias = (const float*)d_in[2];
    float* out = (float*)d_out;
    _Float16* wsg = (_Float16*)d_ws;   // 512 KB fragment-packed W halves

    hipLaunchKernelGGL(split_w_kernel, dim3(16384 / 256), dim3(256),
                       0, stream, W, wsg);
    hipLaunchKernelGGL(router_kernel, dim3(S_TOT / RPB), dim3(1024),
                       0, stream, x, wsg, bias, out, out + S_TOT * TOPK);
}

// Round 19
// 42.167 us; speedup vs baseline: 3.0211x; 1.1869x over previous
//
#include <hip/hip_runtime.h>
#include <math.h>

#define N_EXP 64
#define TOPK 8
#define TOPK_G 4
#define D_DIM 2048
#define S_TOT 16384
#define RPB 64            // rows per block
#define NBUF 4            // LDS pipeline depth
#define NCH 32            // K chunks of 64

typedef _Float16 half8 __attribute__((ext_vector_type(8)));
typedef float f32x4 __attribute__((ext_vector_type(4)));

typedef __attribute__((address_space(1))) const unsigned int ga_u32;
typedef __attribute__((address_space(3))) unsigned int ls_u32;
#define GLL(src, dst) \
    __builtin_amdgcn_global_load_lds((ga_u32*)(src), (ls_u32*)(dst), 16, 0, 0)
#define VM(n) asm volatile("s_waitcnt vmcnt(" #n ")" ::: "memory")
#define BAR() do { asm volatile("" ::: "memory"); \
                   __builtin_amdgcn_s_barrier(); \
                   asm volatile("" ::: "memory"); } while (0)

// kernel 0: split W fp32 -> fp16 (h, l*2^11), packed per K=64 chunk
// (R17/R18-proven verbatim): chunk c (8192 halfs) = Wh[(kh*4+t4)*512 +
// m16*32 + slot*8] (4096) || Wl (4096), slot = (kb + (m16>>1)) & 3.
__global__ void split_w_kernel(const float* __restrict__ W,
                               _Float16* __restrict__ wsg) {
    int t = blockIdx.x * blockDim.x + threadIdx.x;   // 32c*2kh*4t4*16m*4kb = 16384
    if (t >= 16384) return;
    const int c   = t >> 9;
    const int kh  = (t >> 8) & 1;
    const int t4  = (t >> 6) & 3;
    const int m16 = (t >> 2) & 15;
    const int kb  = t & 3;
    const int slot = (kb + (m16 >> 1)) & 3;
    _Float16* dh = wsg + (size_t)c * 8192 + (kh * 4 + t4) * 512 + m16 * 32 + slot * 8;
    _Float16* dl = dh + 4096;
    const float* s = W + (size_t)(t4 * 16 + m16) * D_DIM + c * 64 + kh * 32 + kb * 8;
#pragma unroll
    for (int i = 0; i < 8; ++i) {
        float f = s[i];
        _Float16 h = (_Float16)f;
        dh[i] = h;
        dl[i] = (_Float16)((f - (float)h) * 2048.0f);
    }
}

// kernel 1: fused fp16x3 MFMA router (R18 skeleton). ONLY change vs R18:
// SINGLE barrier per chunk (lookahead 2, VM(4)). The trailing "reads-done"
// barrier is redundant at lookahead 2: STAGE(c+2) overwrites buf (c-2)%4,
// whose readers (COMPUTE(c-2)) all finished before BAR(c-1) < STAGE(c+2).
__launch_bounds__(1024)
__global__ void router_kernel(const float* __restrict__ x,
                              const _Float16* __restrict__ wsg,
                              const float* __restrict__ bias,
                              float* __restrict__ out_idx,
                              float* __restrict__ out_w)
{
    __shared__ __align__(16) float    xs[NBUF][4096];   // 64 KB x chunks [64r][64k] swz
    __shared__ __align__(16) _Float16 wh[NBUF][8192];   // 64 KB Wh||Wl chunks

    const int tid  = threadIdx.x;
    const int w    = tid >> 6;        // wave 0..15
    const int et   = w & 3;           // expert tile
    const int kh   = (w >> 2) & 1;    // K half within chunk
    const int rh   = w >> 3;          // row half
    const int lane = tid & 63;
    const int m16  = lane & 15;
    const int kb   = lane >> 4;
    const int row0 = blockIdx.x * RPB;

    // x staging: thread stages granule gidx (16B) at LDS float pos gidx*4,
    // from the inverse-swizzled global position (slot = (quad + row) & 7)
    const int gidx = tid;                   // 0..1023
    const int gr = gidx >> 4;               // row 0..63
    const int gs = gidx & 15;
    const int gh = gs >> 3;                 // k-half of granule
    const int gq = ((gs & 7) - gr) & 7;     // global quad for this slot
    const float*    xsrc = x + (size_t)(row0 + gr) * D_DIM + gh * 32 + gq * 4;
    const _Float16* wsrc = wsg + (size_t)tid * 8;

#define STAGE(c, b) do { \
        GLL(xsrc + (size_t)(c) * 64, &xs[b][w * 256]); \
        GLL(wsrc + (size_t)(c) * 8192, &wh[b][w * 512]); \
    } while (0)

    f32x4 accHH[2], accHL[2], accLH[2];
#pragma unroll
    for (int mt = 0; mt < 2; ++mt) {
        accHH[mt] = (f32x4)0.0f; accHL[mt] = (f32x4)0.0f; accLH[mt] = (f32x4)0.0f;
    }

#define COMPUTE(b) do { \
        const int boff = (kh * 4 + et) * 512 + m16 * 32 + ((kb + (m16 >> 1)) & 3) * 8; \
        const half8 bh = *(const half8*)&wh[b][boff]; \
        const half8 bl = *(const half8*)&wh[b][4096 + boff]; \
        _Pragma("unroll") \
        for (int mt = 0; mt < 2; ++mt) { \
            const int rr = rh * 32 + mt * 16 + m16; \
            const int p0 = rr * 16 + kh * 8 + ((kb * 2 + rr) & 7); \
            const int p1 = rr * 16 + kh * 8 + ((kb * 2 + 1 + rr) & 7); \
            const float4 f0 = *(const float4*)&xs[b][p0 * 4]; \
            const float4 f1 = *(const float4*)&xs[b][p1 * 4]; \
            const float v[8] = {f0.x, f0.y, f0.z, f0.w, f1.x, f1.y, f1.z, f1.w}; \
            half8 xh, xl; \
            _Pragma("unroll") \
            for (int i = 0; i < 8; ++i) { \
                _Float16 h = (_Float16)v[i]; \
                xh[i] = h; \
                xl[i] = (_Float16)((v[i] - (float)h) * 2048.0f); \
            } \
            accHH[mt] = __builtin_amdgcn_mfma_f32_16x16x32_f16(xh, bh, accHH[mt], 0, 0, 0); \
            accHL[mt] = __builtin_amdgcn_mfma_f32_16x16x32_f16(xh, bl, accHL[mt], 0, 0, 0); \
            accLH[mt] = __builtin_amdgcn_mfma_f32_16x16x32_f16(xl, bh, accLH[mt], 0, 0, 0); \
        } \
    } while (0)

    // prologue: stage chunks 0,1
    STAGE(0, 0); STAGE(1, 1);

    for (int c = 0; c < NCH; ++c) {
        if (c + 2 < NCH)        { STAGE(c + 2, (c + 2) & 3); VM(4); }
        else if (c == NCH - 2)  VM(2);
        else                    VM(0);
        BAR();               // all waves' chunk-c DMA landed; buffer (c-2)%4
                             // safely re-staged (its readers pre-date BAR(c-1))
        COMPUTE(c & 3);
    }
#undef STAGE
#undef COMPUTE
    BAR();                   // K-loop LDS reads done before overlay writes

    // ---- epilogue: lg/bias overlay the xs buffers ----
    float* lgp = (float*)&xs[0][0];        // RPB*68 = 4352 floats
    float* bsp = lgp + RPB * 68;           // 64 floats

    if (tid < N_EXP) bsp[tid] = bias[tid];

    const float inv2048 = 1.0f / 2048.0f;
    // 2-phase kh reduction (D frag: row = rh*32 + mt*16 + kb*4 + r, col = et*16+m16)
    if (kh == 0) {
#pragma unroll
        for (int mt = 0; mt < 2; ++mt)
#pragma unroll
            for (int r = 0; r < 4; ++r)
                lgp[(rh * 32 + mt * 16 + kb * 4 + r) * 68 + et * 16 + m16] =
                    accHH[mt][r] + (accHL[mt][r] + accLH[mt][r]) * inv2048;
    }
    __syncthreads();
    if (kh == 1) {
#pragma unroll
        for (int mt = 0; mt < 2; ++mt)
#pragma unroll
            for (int r = 0; r < 4; ++r)
                lgp[(rh * 32 + mt * 16 + kb * 4 + r) * 68 + et * 16 + m16] +=
                    accHH[mt][r] + (accHL[mt][r] + accLH[mt][r]) * inv2048;
    }
    __syncthreads();

    // sigmoid in place (64 rows x 64 experts; threads 0..511)
    if (tid < RPB * 8) {
        const int rg = tid >> 3, sl = tid & 7;
#pragma unroll
        for (int j = 0; j < 8; ++j) {
            const int idx = rg * 68 + sl * 8 + j;
            lgp[idx] = 1.0f / (1.0f + expf(-lgp[idx]));
        }
    }
    __syncthreads();

    // grouped top-k: R7-proven parallel selection (ties -> lower index)
    if (tid < RPB * 8) {
        const int rg = tid >> 3;
        const int sl = tid & 7;
        const int row = row0 + rg;

        float bsc[8];
        float gm = -INFINITY;
#pragma unroll
        for (int j = 0; j < 8; ++j) {
            bsc[j] = lgp[rg * 68 + sl * 8 + j] + bsp[sl * 8 + j];
            gm = fmaxf(gm, bsc[j]);
        }

        int grank = 0;
#pragma unroll
        for (int s = 1; s < 8; ++s) {
            float og = __shfl_xor(gm, s, 8);
            int   osl = sl ^ s;
            if (og > gm || (og == gm && osl < sl)) ++grank;
        }
        unsigned alive = (grank < TOPK_G) ? 0xFFu : 0u;

        float wsum = 0.f;
        float myw = 0.f;
        const int orow = row * TOPK;
        for (int k = 0; k < TOPK; ++k) {
            float bv = -INFINITY; int be = 9999;
#pragma unroll
            for (int j = 0; j < 8; ++j) {
                if (alive & (1u << j)) {
                    if (bsc[j] > bv) { bv = bsc[j]; be = sl * 8 + j; }
                }
            }
#pragma unroll
            for (int s = 1; s < 8; s <<= 1) {
                float ov = __shfl_xor(bv, s, 8);
                int   oe = __shfl_xor(be, s, 8);
                if (ov > bv || (ov == bv && oe < be)) { bv = ov; be = oe; }
            }
            const float wr = lgp[rg * 68 + be];
            wsum += wr;
            if ((be >> 3) == sl) alive &= ~(1u << (be & 7));
            if (sl == k) { out_idx[orow + k] = (float)be; myw = wr; }
        }
        const float inv = 1.0f / (wsum + 1e-20f);
        out_w[orow + sl] = myw * inv;
    }
}

extern "C" void kernel_launch(void* const* d_in, const int* in_sizes, int n_in,
                              void* d_out, int out_size, void* d_ws, size_t ws_size,
                              hipStream_t stream) {
    const float* x    = (const float*)d_in[0];
    const float* W    = (const float*)d_in[1];
    const float* bias = (const float*)d_in[2];
    float* out = (float*)d_out;
    _Float16* wsg = (_Float16*)d_ws;   // 512 KB fragment-packed W halves

    hipLaunchKernelGGL(split_w_kernel, dim3(16384 / 256), dim3(256),
                       0, stream, W, wsg);
    hipLaunchKernelGGL(router_kernel, dim3(S_TOT / RPB), dim3(1024),
                       0, stream, x, wsg, bias, out, out + S_TOT * TOPK);
}

// Round 20
// 38.847 us; speedup vs baseline: 3.2793x; 1.0855x over previous
//
#include <hip/hip_runtime.h>
#include <math.h>

#define N_EXP 64
#define TOPK 8
#define TOPK_G 4
#define D_DIM 2048
#define S_TOT 16384
#define RPB 64            // rows per block
#define NBUF 4            // LDS pipeline depth
#define NCH 32            // K chunks of 64

typedef _Float16 half8 __attribute__((ext_vector_type(8)));
typedef float f32x4 __attribute__((ext_vector_type(4)));

typedef __attribute__((address_space(1))) const unsigned int ga_u32;
typedef __attribute__((address_space(3))) unsigned int ls_u32;
#define GLL(src, dst) \
    __builtin_amdgcn_global_load_lds((ga_u32*)(src), (ls_u32*)(dst), 16, 0, 0)
#define VM(n) asm volatile("s_waitcnt vmcnt(" #n ")" ::: "memory")
#define BAR() do { asm volatile("" ::: "memory"); \
                   __builtin_amdgcn_s_barrier(); \
                   asm volatile("" ::: "memory"); } while (0)

// kernel 0: split W fp32 -> fp16 (h, l*2^11), packed per K=64 chunk
// (R17/R18/R19-proven verbatim): chunk c (8192 halfs) = Wh[(kh*4+t4)*512 +
// m16*32 + slot*8] (4096) || Wl (4096), slot = (kb + (m16>>1)) & 3.
__global__ void split_w_kernel(const float* __restrict__ W,
                               _Float16* __restrict__ wsg) {
    int t = blockIdx.x * blockDim.x + threadIdx.x;   // 32c*2kh*4t4*16m*4kb = 16384
    if (t >= 16384) return;
    const int c   = t >> 9;
    const int kh  = (t >> 8) & 1;
    const int t4  = (t >> 6) & 3;
    const int m16 = (t >> 2) & 15;
    const int kb  = t & 3;
    const int slot = (kb + (m16 >> 1)) & 3;
    _Float16* dh = wsg + (size_t)c * 8192 + (kh * 4 + t4) * 512 + m16 * 32 + slot * 8;
    _Float16* dl = dh + 4096;
    const float* s = W + (size_t)(t4 * 16 + m16) * D_DIM + c * 64 + kh * 32 + kb * 8;
#pragma unroll
    for (int i = 0; i < 8; ++i) {
        float f = s[i];
        _Float16 h = (_Float16)f;
        dh[i] = h;
        dl[i] = (_Float16)((f - (float)h) * 2048.0f);
    }
}

// kernel 1: fused fp16x3 MFMA router (R19 skeleton, single barrier/chunk).
// ONLY change vs R19: wave decomposition (rh 0..3, kh 0..1, eh 0..1) — each
// wave owns 16 rows and computes TWO expert tiles (et = eh*2+q), so each x
// element is split once per (rh,kh) pair instead of 4x, and A-frag LDS reads
// halve. Pipeline/DMA/layout/epilogue otherwise byte-identical.
__launch_bounds__(1024)
__global__ void router_kernel(const float* __restrict__ x,
                              const _Float16* __restrict__ wsg,
                              const float* __restrict__ bias,
                              float* __restrict__ out_idx,
                              float* __restrict__ out_w)
{
    __shared__ __align__(16) float    xs[NBUF][4096];   // 64 KB x chunks [64r][64k] swz
    __shared__ __align__(16) _Float16 wh[NBUF][8192];   // 64 KB Wh||Wl chunks

    const int tid  = threadIdx.x;
    const int w    = tid >> 6;        // wave 0..15
    const int rh   = w >> 2;          // row quarter 0..3 (16 rows)
    const int kh   = (w >> 1) & 1;    // K half within chunk
    const int eh   = w & 1;           // expert half (tiles eh*2, eh*2+1)
    const int lane = tid & 63;
    const int m16  = lane & 15;
    const int kb   = lane >> 4;
    const int row0 = blockIdx.x * RPB;

    // x staging: thread stages granule gidx (16B) at LDS float pos gidx*4,
    // from the inverse-swizzled global position (slot = (quad + row) & 7)
    const int gidx = tid;                   // 0..1023
    const int gr = gidx >> 4;               // row 0..63
    const int gs = gidx & 15;
    const int gh = gs >> 3;                 // k-half of granule
    const int gq = ((gs & 7) - gr) & 7;     // global quad for this slot
    const float*    xsrc = x + (size_t)(row0 + gr) * D_DIM + gh * 32 + gq * 4;
    const _Float16* wsrc = wsg + (size_t)tid * 8;

#define STAGE(c, b) do { \
        GLL(xsrc + (size_t)(c) * 64, &xs[b][w * 256]); \
        GLL(wsrc + (size_t)(c) * 8192, &wh[b][w * 512]); \
    } while (0)

    f32x4 accHH[2], accHL[2], accLH[2];
#pragma unroll
    for (int q = 0; q < 2; ++q) {
        accHH[q] = (f32x4)0.0f; accHL[q] = (f32x4)0.0f; accLH[q] = (f32x4)0.0f;
    }

#define COMPUTE(b) do { \
        const int rr = rh * 16 + m16; \
        const int p0 = rr * 16 + kh * 8 + ((kb * 2 + rr) & 7); \
        const int p1 = rr * 16 + kh * 8 + ((kb * 2 + 1 + rr) & 7); \
        const float4 f0 = *(const float4*)&xs[b][p0 * 4]; \
        const float4 f1 = *(const float4*)&xs[b][p1 * 4]; \
        const float v[8] = {f0.x, f0.y, f0.z, f0.w, f1.x, f1.y, f1.z, f1.w}; \
        half8 xh, xl; \
        _Pragma("unroll") \
        for (int i = 0; i < 8; ++i) { \
            _Float16 h = (_Float16)v[i]; \
            xh[i] = h; \
            xl[i] = (_Float16)((v[i] - (float)h) * 2048.0f); \
        } \
        _Pragma("unroll") \
        for (int q = 0; q < 2; ++q) { \
            const int et = eh * 2 + q; \
            const int boff = (kh * 4 + et) * 512 + m16 * 32 + ((kb + (m16 >> 1)) & 3) * 8; \
            const half8 bh = *(const half8*)&wh[b][boff]; \
            const half8 bl = *(const half8*)&wh[b][4096 + boff]; \
            accHH[q] = __builtin_amdgcn_mfma_f32_16x16x32_f16(xh, bh, accHH[q], 0, 0, 0); \
            accHL[q] = __builtin_amdgcn_mfma_f32_16x16x32_f16(xh, bl, accHL[q], 0, 0, 0); \
            accLH[q] = __builtin_amdgcn_mfma_f32_16x16x32_f16(xl, bh, accLH[q], 0, 0, 0); \
        } \
    } while (0)

    // prologue: stage chunks 0,1
    STAGE(0, 0); STAGE(1, 1);

    for (int c = 0; c < NCH; ++c) {
        if (c + 2 < NCH)        { STAGE(c + 2, (c + 2) & 3); VM(4); }
        else if (c == NCH - 2)  VM(2);
        else                    VM(0);
        BAR();               // all waves' chunk-c DMA landed; buffer (c-2)%4
                             // safely re-staged (its readers pre-date BAR(c-1))
        COMPUTE(c & 3);
    }
#undef STAGE
#undef COMPUTE
    BAR();                   // K-loop LDS reads done before overlay writes

    // ---- epilogue: lg/bias overlay the xs buffers ----
    float* lgp = (float*)&xs[0][0];        // RPB*68 = 4352 floats
    float* bsp = lgp + RPB * 68;           // 64 floats

    if (tid < N_EXP) bsp[tid] = bias[tid];

    const float inv2048 = 1.0f / 2048.0f;
    // 2-phase kh reduction (D frag: row = rh*16 + kb*4 + r, col = (eh*2+q)*16+m16)
    if (kh == 0) {
#pragma unroll
        for (int q = 0; q < 2; ++q)
#pragma unroll
            for (int r = 0; r < 4; ++r)
                lgp[(rh * 16 + kb * 4 + r) * 68 + (eh * 2 + q) * 16 + m16] =
                    accHH[q][r] + (accHL[q][r] + accLH[q][r]) * inv2048;
    }
    __syncthreads();
    if (kh == 1) {
#pragma unroll
        for (int q = 0; q < 2; ++q)
#pragma unroll
            for (int r = 0; r < 4; ++r)
                lgp[(rh * 16 + kb * 4 + r) * 68 + (eh * 2 + q) * 16 + m16] +=
                    accHH[q][r] + (accHL[q][r] + accLH[q][r]) * inv2048;
    }
    __syncthreads();

    // sigmoid in place (64 rows x 64 experts; threads 0..511)
    if (tid < RPB * 8) {
        const int rg = tid >> 3, sl = tid & 7;
#pragma unroll
        for (int j = 0; j < 8; ++j) {
            const int idx = rg * 68 + sl * 8 + j;
            lgp[idx] = 1.0f / (1.0f + expf(-lgp[idx]));
        }
    }
    __syncthreads();

    // grouped top-k: R7-proven parallel selection (ties -> lower index)
    if (tid < RPB * 8) {
        const int rg = tid >> 3;
        const int sl = tid & 7;
        const int row = row0 + rg;

        float bsc[8];
        float gm = -INFINITY;
#pragma unroll
        for (int j = 0; j < 8; ++j) {
            bsc[j] = lgp[rg * 68 + sl * 8 + j] + bsp[sl * 8 + j];
            gm = fmaxf(gm, bsc[j]);
        }

        int grank = 0;
#pragma unroll
        for (int s = 1; s < 8; ++s) {
            float og = __shfl_xor(gm, s, 8);
            int   osl = sl ^ s;
            if (og > gm || (og == gm && osl < sl)) ++grank;
        }
        unsigned alive = (grank < TOPK_G) ? 0xFFu : 0u;

        float wsum = 0.f;
        float myw = 0.f;
        const int orow = row * TOPK;
        for (int k = 0; k < TOPK; ++k) {
            float bv = -INFINITY; int be = 9999;
#pragma unroll
            for (int j = 0; j < 8; ++j) {
                if (alive & (1u << j)) {
                    if (bsc[j] > bv) { bv = bsc[j]; be = sl * 8 + j; }
                }
            }
#pragma unroll
            for (int s = 1; s < 8; s <<= 1) {
                float ov = __shfl_xor(bv, s, 8);
                int   oe = __shfl_xor(be, s, 8);
                if (ov > bv || (ov == bv && oe < be)) { bv = ov; be = oe; }
            }
            const float wr = lgp[rg * 68 + be];
            wsum += wr;
            if ((be >> 3) == sl) alive &= ~(1u << (be & 7));
            if (sl == k) { out_idx[orow + k] = (float)be; myw = wr; }
        }
        const float inv = 1.0f / (wsum + 1e-20f);
        out_w[orow + sl] = myw * inv;
    }
}

extern "C" void kernel_launch(void* const* d_in, const int* in_sizes, int n_in,
                              void* d_out, int out_size, void* d_ws, size_t ws_size,
                              hipStream_t stream) {
    const float* x    = (const float*)d_in[0];
    const float* W    = (const float*)d_in[1];
    const float* bias = (const float*)d_in[2];
    float* out = (float*)d_out;
    _Float16* wsg = (_Float16*)d_ws;   // 512 KB fragment-packed W halves

    hipLaunchKernelGGL(split_w_kernel, dim3(16384 / 256), dim3(256),
                       0, stream, W, wsg);
    hipLaunchKernelGGL(router_kernel, dim3(S_TOT / RPB), dim3(1024),
                       0, stream, x, wsg, bias, out, out + S_TOT * TOPK);
}